// Round 4
// baseline (114.408 us; speedup 1.0000x reference)
//
#include <hip/hip_runtime.h>
#include <hip/hip_cooperative_groups.h>

namespace cg = cooperative_groups;

// RerankLoss: margin-ranking hinge over all pos-neg pairs per row.
// scores: [B, L] f32, labels: [B, L] i32 in {0,1}; output: scalar f32.
// out = (1/B) * sum_b [ sum_{i pos, j neg} relu(1 - (s_i - s_j)) / (n_pos*n_neg) ]
//
// Single cooperative launch. Phase 1: 1 wave per sample (4 waves/block),
// ballot-compact pos/neg into per-wave LDS, pair-sweep negatives via float4
// LDS broadcast, block-reduce -> ws[blockIdx]. grid.sync(). Phase 2: block 0
// reduces the 1024 partials and writes out[0] (no memset, no atomics).

constexpr int L  = 200;
constexpr int LQ = L / 4;           // 50 quads per row
constexpr float MARGIN = 1.0f;

__global__ __launch_bounds__(256) void rerank_coop(
    const float* __restrict__ scores,
    const int*   __restrict__ labels,
    float*       __restrict__ out,
    float*       __restrict__ ws,
    int B)
{
    __shared__ __align__(16) float posv[4][208];
    __shared__ __align__(16) float negv[4][208];
    __shared__ float wpart[4];

    const int tid  = threadIdx.x;
    const int w    = tid >> 6;       // wave id 0..3
    const int lane = tid & 63;
    const int b    = blockIdx.x * 4 + w;   // sample for this wave
    const float invB = 1.0f / (float)B;

    // --- coalesced vector load: lanes 0..49 hold 4 consecutive elements ---
    float4 sv = make_float4(0.f, 0.f, 0.f, 0.f);
    int4   lv = make_int4(0, 0, 0, 0);
    const bool act = lane < LQ;
    if (act) {
        sv = ((const float4*)(scores + (long)b * L))[lane];
        lv = ((const int4*)(labels + (long)b * L))[lane];
    }
    const float ev[4] = {sv.x, sv.y, sv.z, sv.w};
    const int   lb[4] = {lv.x, lv.y, lv.z, lv.w};

    // --- ballot compaction: unique LDS slot = base + popc(mask & lower) ---
    const unsigned long long lower = (1ull << lane) - 1ull;
    int npos = 0, nneg = 0;
#pragma unroll
    for (int j = 0; j < 4; ++j) {
        const bool isp = act && (lb[j] != 0);
        const bool isn = act && (lb[j] == 0);
        const unsigned long long mp = __ballot(isp);
        const unsigned long long mn = __ballot(isn);
        if (isp) posv[w][npos + __popcll(mp & lower)] = ev[j];
        if (isn) negv[w][nneg + __popcll(mn & lower)] = ev[j];
        npos += __popcll(mp);      // wave-uniform
        nneg += __popcll(mn);
    }

    // pad negatives to a multiple of 4; relu(c - 3e38) == 0 kills pad terms
    const int nneg4 = (nneg + 3) & ~3;
    if (lane < nneg4 - nneg) negv[w][nneg + lane] = -3.0e38f;
    __syncthreads();               // drain LDS writes

    // --- pair loop: lane owns positive i; negatives via LDS broadcast ---
    float acc = 0.0f;
    const float4* nv = (const float4*)&negv[w][0];
    const int nq = nneg4 >> 2;
    for (int i = lane; i < npos; i += 64) {
        const float c = MARGIN - posv[w][i];
        float a0 = 0.f, a1 = 0.f, a2 = 0.f, a3 = 0.f;
        for (int j = 0; j < nq; ++j) {
            float4 n = nv[j];
            a0 += fmaxf(c + n.x, 0.0f);
            a1 += fmaxf(c + n.y, 0.0f);
            a2 += fmaxf(c + n.z, 0.0f);
            a3 += fmaxf(c + n.w, 0.0f);
        }
        acc += (a0 + a1) + (a2 + a3);
    }

    // wave64 reduce
    for (int o = 32; o; o >>= 1) acc += __shfl_down(acc, o, 64);
    if (lane == 0) {
        const float np = (float)npos * (float)nneg;
        wpart[w] = (np > 0.0f) ? (acc / np) * invB : 0.0f;
    }
    __syncthreads();
    if (tid == 0) {
        ws[blockIdx.x] = (wpart[0] + wpart[1]) + (wpart[2] + wpart[3]);
    }

    __threadfence();               // device-scope release (cross-XCD visibility)
    cg::this_grid().sync();

    // --- phase 2: block 0 reduces the gridDim.x partials ---
    if (blockIdx.x == 0) {
        const int nb = gridDim.x;            // 1024
        float v = 0.0f;
        const float4* pv = (const float4*)ws;
        for (int i = tid; i < (nb >> 2); i += 256) {
            float4 q = pv[i];
            v += (q.x + q.y) + (q.z + q.w);
        }
        for (int o = 32; o; o >>= 1) v += __shfl_down(v, o, 64);
        __shared__ float fsum[4];
        if (lane == 0) fsum[w] = v;
        __syncthreads();
        if (tid == 0) out[0] = (fsum[0] + fsum[1]) + (fsum[2] + fsum[3]);
    }
}

extern "C" void kernel_launch(void* const* d_in, const int* in_sizes, int n_in,
                              void* d_out, int out_size, void* d_ws, size_t ws_size,
                              hipStream_t stream)
{
    const float* scores = (const float*)d_in[0];
    const int*   labels = (const int*)d_in[1];
    float*       out    = (float*)d_out;
    float*       ws     = (float*)d_ws;
    int B = in_sizes[0] / L;

    void* args[] = {(void*)&scores, (void*)&labels, (void*)&out, (void*)&ws, (void*)&B};
    hipLaunchCooperativeKernel((void*)rerank_coop, dim3(B / 4), dim3(256),
                               args, 0, stream);
}

// Round 5
// 13.699 us; speedup vs baseline: 8.3516x; 8.3516x over previous
//
#include <hip/hip_runtime.h>

// RerankLoss: margin-ranking hinge over all pos-neg pairs per row.
// scores: [B, L] f32, labels: [B, L] i32 in {0,1}; output: scalar f32.
// out = (1/B) * sum_b [ sum_{i pos, j neg} relu(1 - (s_i - s_j)) / (n_pos*n_neg) ]
//
// Two dispatches (empirically fastest structure: in-graph fill node costs
// ~12us, cooperative grid.sync costs ~95us on gfx950):
//   k1: 1024 blocks x 256 thr, one wave per sample, ballot-compaction,
//       float4 LDS-broadcast pair sweep, block partial -> ws[blockIdx].
//   k2: one wave, 64 lanes x float4 = 1024 partials, reduce, write out.

constexpr int L  = 200;
constexpr int LQ = L / 4;           // 50 quads per row
constexpr float MARGIN = 1.0f;

__global__ __launch_bounds__(256) void rerank_part(
    const float* __restrict__ scores,
    const int*   __restrict__ labels,
    float*       __restrict__ ws,
    float invB)
{
    __shared__ __align__(16) float posv[4][208];
    __shared__ __align__(16) float negv[4][208];
    __shared__ float wpart[4];

    const int tid  = threadIdx.x;
    const int w    = tid >> 6;       // wave id 0..3
    const int lane = tid & 63;
    const int b    = blockIdx.x * 4 + w;   // sample for this wave

    // --- coalesced vector load: lanes 0..49 hold 4 consecutive elements ---
    float4 sv = make_float4(0.f, 0.f, 0.f, 0.f);
    int4   lv = make_int4(0, 0, 0, 0);
    const bool act = lane < LQ;
    if (act) {
        sv = ((const float4*)(scores + (long)b * L))[lane];
        lv = ((const int4*)(labels + (long)b * L))[lane];
    }
    const float ev[4] = {sv.x, sv.y, sv.z, sv.w};
    const int   lb[4] = {lv.x, lv.y, lv.z, lv.w};

    // --- ballot compaction: unique LDS slot = base + popc(mask & lower) ---
    const unsigned long long lower = (1ull << lane) - 1ull;
    int npos = 0, nneg = 0;
#pragma unroll
    for (int j = 0; j < 4; ++j) {
        const bool isp = act && (lb[j] != 0);
        const bool isn = act && (lb[j] == 0);
        const unsigned long long mp = __ballot(isp);
        const unsigned long long mn = __ballot(isn);
        if (isp) posv[w][npos + __popcll(mp & lower)] = ev[j];
        if (isn) negv[w][nneg + __popcll(mn & lower)] = ev[j];
        npos += __popcll(mp);      // wave-uniform
        nneg += __popcll(mn);
    }

    // pad negatives to a multiple of 4; relu(c - 3e38) == 0 kills pad terms
    const int nneg4 = (nneg + 3) & ~3;
    if (lane < nneg4 - nneg) negv[w][nneg + lane] = -3.0e38f;
    __syncthreads();               // drain LDS writes

    // --- pair loop: lane owns positive i; negatives via LDS broadcast ---
    float acc = 0.0f;
    const float4* nv = (const float4*)&negv[w][0];
    const int nq = nneg4 >> 2;
    for (int i = lane; i < npos; i += 64) {
        const float c = MARGIN - posv[w][i];
        float a0 = 0.f, a1 = 0.f, a2 = 0.f, a3 = 0.f;
        for (int j = 0; j < nq; ++j) {
            float4 n = nv[j];
            a0 += fmaxf(c + n.x, 0.0f);
            a1 += fmaxf(c + n.y, 0.0f);
            a2 += fmaxf(c + n.z, 0.0f);
            a3 += fmaxf(c + n.w, 0.0f);
        }
        acc += (a0 + a1) + (a2 + a3);
    }

    // wave64 reduce
    for (int o = 32; o; o >>= 1) acc += __shfl_down(acc, o, 64);
    if (lane == 0) {
        const float np = (float)npos * (float)nneg;
        wpart[w] = (np > 0.0f) ? (acc / np) * invB : 0.0f;
    }
    __syncthreads();
    if (tid == 0) {
        ws[blockIdx.x] = (wpart[0] + wpart[1]) + (wpart[2] + wpart[3]);
    }
}

// nb partials, nb == 1024: 64 lanes x float4 covers them in one load round.
__global__ __launch_bounds__(64) void rerank_final(
    const float* __restrict__ ws,
    float*       __restrict__ out,
    int nq)                         // number of float4 quads (nb/4 = 256)
{
    const int lane = threadIdx.x;
    float v = 0.0f;
    const float4* pv = (const float4*)ws;
    for (int i = lane; i < nq; i += 64) {     // nq=256 -> 4 quads per lane
        float4 q = pv[i];
        v += (q.x + q.y) + (q.z + q.w);
    }
    for (int o = 32; o; o >>= 1) v += __shfl_down(v, o, 64);
    if (lane == 0) out[0] = v;
}

extern "C" void kernel_launch(void* const* d_in, const int* in_sizes, int n_in,
                              void* d_out, int out_size, void* d_ws, size_t ws_size,
                              hipStream_t stream)
{
    const float* scores = (const float*)d_in[0];
    const int*   labels = (const int*)d_in[1];
    float*       out    = (float*)d_out;
    float*       ws     = (float*)d_ws;
    const int B  = in_sizes[0] / L;   // 4096
    const int nb = B / 4;             // 1024 blocks / partials

    rerank_part<<<nb, 256, 0, stream>>>(scores, labels, ws, 1.0f / (float)B);
    rerank_final<<<1, 64, 0, stream>>>(ws, out, nb / 4);
}